// Round 5
// baseline (114.096 us; speedup 1.0000x reference)
//
#include <hip/hip_runtime.h>

#define T_STEPS 128
#define BR      256     // output rows per block
#define K_LGN   7       // register synapse slots per lane (lgn): 7*256=1792 >> mean 1280
#define K_BKG   3       // bkg: 3*256=768 >> mean 512

// ---------------------------------------------------------------------------
// Fused prep: low gids build uint4 spike masks (bit t of word q = spike at
// t=q*32+bit), high gids build BR-granular CSR bounds for both inputs.
// ---------------------------------------------------------------------------
__global__ __launch_bounds__(256) void prep_kernel(
    const float* __restrict__ lgn_spikes, int lgn_C, uint4* __restrict__ lgn_mask,
    const float* __restrict__ bkg_spikes, int bkg_C, uint4* __restrict__ bkg_mask,
    const int* __restrict__ lgn_rows, int nnz_l, int* __restrict__ lgn_bound,
    const int* __restrict__ bkg_rows, int nnz_b, int* __restrict__ bkg_bound,
    int nb)
{
    int gid = blockIdx.x * 256 + threadIdx.x;
    int totC = lgn_C + bkg_C;

    if (gid < totC) {
        const float* sp; uint4* mask; int C, cc;
        if (gid < lgn_C) { sp = lgn_spikes; mask = lgn_mask; C = lgn_C; cc = gid; }
        else             { sp = bkg_spikes; mask = bkg_mask; C = bkg_C; cc = gid - lgn_C; }
        unsigned int m0 = 0u, m1 = 0u, m2 = 0u, m3 = 0u;
        #pragma unroll 4
        for (int t = 0; t < 32; ++t) {
            if (sp[(size_t)(t)       * C + cc] != 0.0f) m0 |= (1u << t);
            if (sp[(size_t)(t +  32) * C + cc] != 0.0f) m1 |= (1u << t);
            if (sp[(size_t)(t +  64) * C + cc] != 0.0f) m2 |= (1u << t);
            if (sp[(size_t)(t +  96) * C + cc] != 0.0f) m3 |= (1u << t);
        }
        mask[cc] = make_uint4(m0, m1, m2, m3);
        return;
    }
    int g = gid - totC;
    if (g <= nb) {
        int target = g * BR;
        {
            int lo = 0, hi = nnz_l;
            while (lo < hi) { int mid = (lo + hi) >> 1; if (lgn_rows[mid] < target) lo = mid + 1; else hi = mid; }
            lgn_bound[g] = lo;
        }
        {
            int lo = 0, hi = nnz_b;
            while (lo < hi) { int mid = (lo + hi) >> 1; if (bkg_rows[mid] < target) lo = mid + 1; else hi = mid; }
            bkg_bound[g] = lo;
        }
    }
}

// ---------------------------------------------------------------------------
// Main: block = 256 output rows. Each lane register-loads its ~7 synapses
// (row, w, uint4 mask) ONCE (coalesced, statically indexed — no scratch).
// Then 4 passes over t-words q: zero 32KB tile acc[row][t^(row&31)], ctz-
// scatter set bits via ds_add (same row, diff t -> DIFFERENT banks), write
// 32 planes with 1KB-per-block contiguity. Output written exactly once.
// ---------------------------------------------------------------------------
__global__ __launch_bounds__(256, 4) void sparse_scatter_kernel(
    const int* __restrict__ lgn_rows, const int* __restrict__ lgn_cols,
    const float* __restrict__ lgn_w,  const int* __restrict__ lgn_bound,
    const int* __restrict__ bkg_rows, const int* __restrict__ bkg_cols,
    const float* __restrict__ bkg_w,  const int* __restrict__ bkg_bound,
    const uint4* __restrict__ lgn_mask, const uint4* __restrict__ bkg_mask,
    int R, float* __restrict__ out)
{
    __shared__ float acc[BR * 32];   // 32 KB, [row][t-swizzled]
    const int tid = threadIdx.x;
    const int b   = blockIdx.x;
    const int r0  = b * BR;

    const int ls = lgn_bound[b], le = lgn_bound[b + 1];
    const int bs = bkg_bound[b], be = bkg_bound[b + 1];

    // ---- register load phase (statically indexed; invalid slots mask=0)
    int   lrow[K_LGN]; float lw[K_LGN]; uint4 lm[K_LGN];
    #pragma unroll
    for (int k = 0; k < K_LGN; ++k) {
        int i = ls + tid + k * 256;
        bool v = i < le;
        lrow[k] = v ? (lgn_rows[i] - r0) : 0;
        lw[k]   = v ? lgn_w[i] : 0.0f;
        lm[k]   = v ? lgn_mask[lgn_cols[i]] : make_uint4(0u, 0u, 0u, 0u);
    }
    int   brow[K_BKG]; float bw[K_BKG]; uint4 bm[K_BKG];
    #pragma unroll
    for (int k = 0; k < K_BKG; ++k) {
        int i = bs + tid + k * 256;
        bool v = i < be;
        brow[k] = v ? (bkg_rows[i] - r0) : 0;
        bw[k]   = v ? bkg_w[i] : 0.0f;
        bm[k]   = v ? bkg_mask[bkg_cols[i]] : make_uint4(0u, 0u, 0u, 0u);
    }

    #define SCATTER_WORD(mw, row, wv)                                       \
        while (mw) {                                                        \
            int t = __builtin_ctz(mw); mw &= mw - 1;                        \
            atomicAdd(&acc[(row) * 32 + (t ^ ((row) & 31))], wv);           \
        }

    #pragma unroll
    for (int q = 0; q < 4; ++q) {
        // zero tile (conflict-free: consecutive lanes, consecutive addrs)
        #pragma unroll
        for (int z = 0; z < 32; ++z) acc[z * 256 + tid] = 0.0f;
        __syncthreads();

        // scatter from registers (q is unroll-static -> direct reg select)
        #pragma unroll
        for (int k = 0; k < K_LGN; ++k) {
            unsigned int mw = (q == 0) ? lm[k].x : (q == 1) ? lm[k].y
                            : (q == 2) ? lm[k].z : lm[k].w;
            int row = lrow[k]; float wv = lw[k];
            SCATTER_WORD(mw, row, wv)
        }
        #pragma unroll
        for (int k = 0; k < K_BKG; ++k) {
            unsigned int mw = (q == 0) ? bm[k].x : (q == 1) ? bm[k].y
                            : (q == 2) ? bm[k].z : bm[k].w;
            int row = brow[k]; float wv = bw[k];
            SCATTER_WORD(mw, row, wv)
        }
        // overflow tails (statistically never taken; required for correctness)
        for (int i = ls + tid + K_LGN * 256; i < le; i += 256) {
            int row = lgn_rows[i] - r0; float wv = lgn_w[i];
            const unsigned int* mp = (const unsigned int*)&lgn_mask[lgn_cols[i]];
            unsigned int mw = mp[q];
            SCATTER_WORD(mw, row, wv)
        }
        for (int i = bs + tid + K_BKG * 256; i < be; i += 256) {
            int row = bkg_rows[i] - r0; float wv = bkg_w[i];
            const unsigned int* mp = (const unsigned int*)&bkg_mask[bkg_cols[i]];
            unsigned int mw = mp[q];
            SCATTER_WORD(mw, row, wv)
        }
        __syncthreads();

        // write 32 planes; per-instr 256B, per-block 1KB per plane
        {
            int row = tid;
            int r = r0 + row;
            if (r < R) {
                #pragma unroll
                for (int t = 0; t < 32; ++t)
                    out[(size_t)(q * 32 + t) * R + r] = acc[row * 32 + (t ^ (row & 31))];
            }
        }
        __syncthreads();
    }
    #undef SCATTER_WORD
}

// ---------------------------------------------------------------------------
// Fallback (small ws): inline binary search + direct float gathers.
// ---------------------------------------------------------------------------
__global__ __launch_bounds__(256) void sparse_fallback_kernel(
    const int* __restrict__ lgn_rows, const int* __restrict__ lgn_cols,
    const float* __restrict__ lgn_w, int nnz_l,
    const int* __restrict__ bkg_rows, const int* __restrict__ bkg_cols,
    const float* __restrict__ bkg_w, int nnz_b,
    const float* __restrict__ lgn_spikes, const float* __restrict__ bkg_spikes,
    int lgn_C, int bkg_C, int R,
    float* __restrict__ out)
{
    int r = blockIdx.x * 256 + threadIdx.x;
    int q = blockIdx.y;
    if (r >= R) return;

    float acc[32];
    #pragma unroll
    for (int t = 0; t < 32; ++t) acc[t] = 0.0f;

    {
        int lo = 0, hi = nnz_l;
        while (lo < hi) { int mid = (lo + hi) >> 1; if (lgn_rows[mid] < r) lo = mid + 1; else hi = mid; }
        for (int i = lo; i < nnz_l && lgn_rows[i] == r; ++i) {
            float wt = lgn_w[i];
            const float* sp = lgn_spikes + (size_t)(q * 32) * lgn_C + lgn_cols[i];
            #pragma unroll
            for (int t = 0; t < 32; ++t)
                acc[t] = fmaf(wt, sp[(size_t)t * lgn_C], acc[t]);
        }
    }
    {
        int lo = 0, hi = nnz_b;
        while (lo < hi) { int mid = (lo + hi) >> 1; if (bkg_rows[mid] < r) lo = mid + 1; else hi = mid; }
        for (int i = lo; i < nnz_b && bkg_rows[i] == r; ++i) {
            float wt = bkg_w[i];
            const float* sp = bkg_spikes + (size_t)(q * 32) * bkg_C + bkg_cols[i];
            #pragma unroll
            for (int t = 0; t < 32; ++t)
                acc[t] = fmaf(wt, sp[(size_t)t * bkg_C], acc[t]);
        }
    }

    float* op = out + (size_t)(q * 32) * R + r;
    #pragma unroll
    for (int t = 0; t < 32; ++t) op[(size_t)t * R] = acc[t];
}

extern "C" void kernel_launch(void* const* d_in, const int* in_sizes, int n_in,
                              void* d_out, int out_size, void* d_ws, size_t ws_size,
                              hipStream_t stream)
{
    const float* lgn_spikes = (const float*)d_in[0];
    const float* bkg_spikes = (const float*)d_in[1];
    const int*   lgn_rows   = (const int*)d_in[2];
    const int*   lgn_cols   = (const int*)d_in[3];
    const float* lgn_w      = (const float*)d_in[4];
    const int*   bkg_rows   = (const int*)d_in[5];
    const int*   bkg_cols   = (const int*)d_in[6];
    const float* bkg_w      = (const float*)d_in[7];
    float* out = (float*)d_out;

    const int nnz_l = in_sizes[2];
    const int nnz_b = in_sizes[5];
    const int lgn_C = in_sizes[0] / T_STEPS;   // 17400
    const int bkg_C = in_sizes[1] / T_STEPS;   // 100
    const int R     = out_size / T_STEPS;      // 200000
    const int NB    = (R + BR - 1) / BR;       // 782 row blocks

    // ws layout (16B-aligned sections)
    size_t off = 0;
    auto take = [&](size_t bytes) { size_t o = off; off = (off + bytes + 15) & ~(size_t)15; return o; };
    size_t o_lgn_bound = take((size_t)(NB + 1) * sizeof(int));
    size_t o_bkg_bound = take((size_t)(NB + 1) * sizeof(int));
    size_t o_lgn_mask  = take((size_t)lgn_C * sizeof(uint4));
    size_t o_bkg_mask  = take((size_t)bkg_C * sizeof(uint4));
    size_t need = off;

    dim3 blk(256);

    if (ws_size >= need) {
        char* ws = (char*)d_ws;
        int* lgn_bound = (int*)(ws + o_lgn_bound);
        int* bkg_bound = (int*)(ws + o_bkg_bound);
        uint4* lgn_mask = (uint4*)(ws + o_lgn_mask);
        uint4* bkg_mask = (uint4*)(ws + o_bkg_mask);

        int prep_threads = (lgn_C + bkg_C) + (NB + 1);
        prep_kernel<<<(prep_threads + 255) / 256, blk, 0, stream>>>(
            lgn_spikes, lgn_C, lgn_mask, bkg_spikes, bkg_C, bkg_mask,
            lgn_rows, nnz_l, lgn_bound, bkg_rows, nnz_b, bkg_bound, NB);

        sparse_scatter_kernel<<<NB, blk, 0, stream>>>(
            lgn_rows, lgn_cols, lgn_w, lgn_bound,
            bkg_rows, bkg_cols, bkg_w, bkg_bound,
            lgn_mask, bkg_mask, R, out);
    } else {
        dim3 grid_main((R + 255) / 256, 4);
        sparse_fallback_kernel<<<grid_main, blk, 0, stream>>>(
            lgn_rows, lgn_cols, lgn_w, nnz_l,
            bkg_rows, bkg_cols, bkg_w, nnz_b,
            lgn_spikes, bkg_spikes,
            lgn_C, bkg_C, R, out);
    }
}

// Round 6
// 91.231 us; speedup vs baseline: 1.2506x; 1.2506x over previous
//
#include <hip/hip_runtime.h>

#define T_STEPS 128

// ---------------------------------------------------------------------------
// Fused prep: low gids build spike bit-masks in PLANE layout mask[q*C + c]
// (bit t2 of plane q = spike at t = q*32 + t2); high gids build row-granular
// CSR starts for both sparse inputs via binary search on the sorted rows.
// ---------------------------------------------------------------------------
__global__ __launch_bounds__(256) void prep_kernel(
    const float* __restrict__ lgn_spikes, int lgn_C, unsigned int* __restrict__ lgn_mask,
    const float* __restrict__ bkg_spikes, int bkg_C, unsigned int* __restrict__ bkg_mask,
    const int* __restrict__ lgn_rows, int nnz_l, int* __restrict__ lgn_start,
    const int* __restrict__ bkg_rows, int nnz_b, int* __restrict__ bkg_start,
    int R)
{
    int gid = blockIdx.x * 256 + threadIdx.x;
    int totC = lgn_C + bkg_C;

    if (gid < totC) {
        const float* sp; unsigned int* mask; int C, cc;
        if (gid < lgn_C) { sp = lgn_spikes; mask = lgn_mask; C = lgn_C; cc = gid; }
        else             { sp = bkg_spikes; mask = bkg_mask; C = bkg_C; cc = gid - lgn_C; }
        unsigned int m0 = 0u, m1 = 0u, m2 = 0u, m3 = 0u;
        #pragma unroll 4
        for (int t = 0; t < 32; ++t) {
            if (sp[(size_t)(t)       * C + cc] != 0.0f) m0 |= (1u << t);
            if (sp[(size_t)(t +  32) * C + cc] != 0.0f) m1 |= (1u << t);
            if (sp[(size_t)(t +  64) * C + cc] != 0.0f) m2 |= (1u << t);
            if (sp[(size_t)(t +  96) * C + cc] != 0.0f) m3 |= (1u << t);
        }
        mask[(size_t)0 * C + cc] = m0;
        mask[(size_t)1 * C + cc] = m1;
        mask[(size_t)2 * C + cc] = m2;
        mask[(size_t)3 * C + cc] = m3;
        return;
    }
    int r = gid - totC;
    if (r <= R) {
        {
            int lo = 0, hi = nnz_l;
            while (lo < hi) { int mid = (lo + hi) >> 1; if (lgn_rows[mid] < r) lo = mid + 1; else hi = mid; }
            lgn_start[r] = lo;
        }
        {
            int lo = 0, hi = nnz_b;
            while (lo < hi) { int mid = (lo + hi) >> 1; if (bkg_rows[mid] < r) lo = mid + 1; else hi = mid; }
            bkg_start[r] = lo;
        }
    }
}

// ---------------------------------------------------------------------------
// Main (round-1 structure, refined): thread = (row PAIR p, t-quarter q).
// acc = float2[32] (row 2p in .x, row 2p+1 in .y) -> 64 registers, no spill
// territory. Each pair-row's synapses are walked as separate CSR sub-ranges
// (no divergent row select). Select = sign-extend bit (bfe) + and + add:
// 3 VALU per (syn,t). Stores: float2 -> 512B contiguous per wave-instr.
// No LDS, no barriers, no atomics.
// ---------------------------------------------------------------------------
__global__ __launch_bounds__(256, 4) void sparse_gather2_kernel(
    const int* __restrict__ lgn_cols, const float* __restrict__ lgn_w,
    const int* __restrict__ lgn_start,
    const int* __restrict__ bkg_cols, const float* __restrict__ bkg_w,
    const int* __restrict__ bkg_start,
    const unsigned int* __restrict__ lgn_mask,  // [4][lgn_C]
    const unsigned int* __restrict__ bkg_mask,  // [4][bkg_C]
    int lgn_C, int bkg_C, int R,
    float* __restrict__ out)
{
    const int p  = blockIdx.x * 256 + threadIdx.x;   // row pair index
    const int q  = blockIdx.y;                       // t-quarter
    const int NP = R >> 1;
    if (p >= NP) return;
    const int r0 = p << 1;

    float2 acc[32];
    #pragma unroll
    for (int t = 0; t < 32; ++t) acc[t] = make_float2(0.0f, 0.0f);

    const unsigned int* lm = lgn_mask + (size_t)q * lgn_C;
    const unsigned int* bm = bkg_mask + (size_t)q * bkg_C;

    // accumulate one synapse's contribution into lane .x or .y (static)
    #define ACC_RANGE(cols_a, w_a, mask_p, i_lo, i_hi, FIELD)                \
        for (int i = (i_lo); i < (i_hi); ++i) {                              \
            int wb = __float_as_int(w_a[i]);                                 \
            unsigned int m = mask_p[cols_a[i]];                              \
            _Pragma("unroll")                                                \
            for (int t = 0; t < 32; ++t) {                                   \
                int sel = ((int)(m << (31 - t))) >> 31;                      \
                acc[t].FIELD += __int_as_float(sel & wb);                    \
            }                                                                \
        }

    {
        int a0 = lgn_start[r0], a1 = lgn_start[r0 + 1], a2 = lgn_start[r0 + 2];
        ACC_RANGE(lgn_cols, lgn_w, lm, a0, a1, x)
        ACC_RANGE(lgn_cols, lgn_w, lm, a1, a2, y)
    }
    {
        int b0 = bkg_start[r0], b1 = bkg_start[r0 + 1], b2 = bkg_start[r0 + 2];
        ACC_RANGE(bkg_cols, bkg_w, bm, b0, b1, x)
        ACC_RANGE(bkg_cols, bkg_w, bm, b1, b2, y)
    }
    #undef ACC_RANGE

    // store: lane p writes rows {2p, 2p+1} as one float2; wave = 512B contig
    float2* op = (float2*)(out + (size_t)(q * 32) * R) + p;
    const size_t strd = (size_t)(R >> 1);   // one t-plane, in float2 units
    #pragma unroll
    for (int t = 0; t < 32; ++t) op[(size_t)t * strd] = acc[t];
}

// ---------------------------------------------------------------------------
// Fallback (small ws): inline binary search + direct float gathers.
// ---------------------------------------------------------------------------
__global__ __launch_bounds__(256) void sparse_fallback_kernel(
    const int* __restrict__ lgn_rows, const int* __restrict__ lgn_cols,
    const float* __restrict__ lgn_w, int nnz_l,
    const int* __restrict__ bkg_rows, const int* __restrict__ bkg_cols,
    const float* __restrict__ bkg_w, int nnz_b,
    const float* __restrict__ lgn_spikes, const float* __restrict__ bkg_spikes,
    int lgn_C, int bkg_C, int R,
    float* __restrict__ out)
{
    int r = blockIdx.x * 256 + threadIdx.x;
    int q = blockIdx.y;
    if (r >= R) return;

    float acc[32];
    #pragma unroll
    for (int t = 0; t < 32; ++t) acc[t] = 0.0f;

    {
        int lo = 0, hi = nnz_l;
        while (lo < hi) { int mid = (lo + hi) >> 1; if (lgn_rows[mid] < r) lo = mid + 1; else hi = mid; }
        for (int i = lo; i < nnz_l && lgn_rows[i] == r; ++i) {
            float wt = lgn_w[i];
            const float* sp = lgn_spikes + (size_t)(q * 32) * lgn_C + lgn_cols[i];
            #pragma unroll
            for (int t = 0; t < 32; ++t)
                acc[t] = fmaf(wt, sp[(size_t)t * lgn_C], acc[t]);
        }
    }
    {
        int lo = 0, hi = nnz_b;
        while (lo < hi) { int mid = (lo + hi) >> 1; if (bkg_rows[mid] < r) lo = mid + 1; else hi = mid; }
        for (int i = lo; i < nnz_b && bkg_rows[i] == r; ++i) {
            float wt = bkg_w[i];
            const float* sp = bkg_spikes + (size_t)(q * 32) * bkg_C + bkg_cols[i];
            #pragma unroll
            for (int t = 0; t < 32; ++t)
                acc[t] = fmaf(wt, sp[(size_t)t * bkg_C], acc[t]);
        }
    }

    float* op = out + (size_t)(q * 32) * R + r;
    #pragma unroll
    for (int t = 0; t < 32; ++t) op[(size_t)t * R] = acc[t];
}

extern "C" void kernel_launch(void* const* d_in, const int* in_sizes, int n_in,
                              void* d_out, int out_size, void* d_ws, size_t ws_size,
                              hipStream_t stream)
{
    const float* lgn_spikes = (const float*)d_in[0];
    const float* bkg_spikes = (const float*)d_in[1];
    const int*   lgn_rows   = (const int*)d_in[2];
    const int*   lgn_cols   = (const int*)d_in[3];
    const float* lgn_w      = (const float*)d_in[4];
    const int*   bkg_rows   = (const int*)d_in[5];
    const int*   bkg_cols   = (const int*)d_in[6];
    const float* bkg_w      = (const float*)d_in[7];
    float* out = (float*)d_out;

    const int nnz_l = in_sizes[2];
    const int nnz_b = in_sizes[5];
    const int lgn_C = in_sizes[0] / T_STEPS;   // 17400
    const int bkg_C = in_sizes[1] / T_STEPS;   // 100
    const int R     = out_size / T_STEPS;      // 200000 (even)

    // ws layout (16B-aligned sections)
    size_t off = 0;
    auto take = [&](size_t bytes) { size_t o = off; off = (off + bytes + 15) & ~(size_t)15; return o; };
    size_t o_lgn_start = take((size_t)(R + 1) * sizeof(int));
    size_t o_bkg_start = take((size_t)(R + 1) * sizeof(int));
    size_t o_lgn_mask  = take((size_t)4 * lgn_C * sizeof(unsigned int));
    size_t o_bkg_mask  = take((size_t)4 * bkg_C * sizeof(unsigned int));
    size_t need = off;

    dim3 blk(256);

    if (ws_size >= need && (R & 1) == 0) {
        char* ws = (char*)d_ws;
        int* lgn_start = (int*)(ws + o_lgn_start);
        int* bkg_start = (int*)(ws + o_bkg_start);
        unsigned int* lgn_mask = (unsigned int*)(ws + o_lgn_mask);
        unsigned int* bkg_mask = (unsigned int*)(ws + o_bkg_mask);

        int prep_threads = (lgn_C + bkg_C) + (R + 1);
        prep_kernel<<<(prep_threads + 255) / 256, blk, 0, stream>>>(
            lgn_spikes, lgn_C, lgn_mask, bkg_spikes, bkg_C, bkg_mask,
            lgn_rows, nnz_l, lgn_start, bkg_rows, nnz_b, bkg_start, R);

        const int NP = R >> 1;                      // 100000 row pairs
        dim3 grid_main((NP + 255) / 256, 4);        // 391 x 4 blocks
        sparse_gather2_kernel<<<grid_main, blk, 0, stream>>>(
            lgn_cols, lgn_w, lgn_start,
            bkg_cols, bkg_w, bkg_start,
            lgn_mask, bkg_mask,
            lgn_C, bkg_C, R, out);
    } else {
        dim3 grid_main((R + 255) / 256, 4);
        sparse_fallback_kernel<<<grid_main, blk, 0, stream>>>(
            lgn_rows, lgn_cols, lgn_w, nnz_l,
            bkg_rows, bkg_cols, bkg_w, nnz_b,
            lgn_spikes, bkg_spikes,
            lgn_C, bkg_C, R, out);
    }
}